// Round 8
// baseline (251.783 us; speedup 1.0000x reference)
//
#include <hip/hip_runtime.h>
#include <math.h>

// MoE router: X[8192,4096] fp32 @ W^T -> logits[8192,64] -> top2 softmax scatter.
// d_out = probs[8192*64] ++ routing_map[8192*64] (floats).
// ws: part [8][8192][64] fp32 (16MB). Wt (W^T, 1MB) staged in d_out scratch.
//
// R1: lane=token raw X reads -> 4x overfetch. Fixed via LDS staging.
// R2: 96us. SMEM W, per-k lgkmcnt(0) drain, duty 30%.
// R3 FAILED: 2 tokens/lane -> regalloc loss. R4 FAILED: DS-instr flood.
// R5: 8x8 reg-tile, x+w via LDS, 1-wave blocks. 92us, VALUBusy 41%.
// R6: 2 barrier-coupled waves/block: null. Occupancy stayed ~10% -> never
//     actually reached 2 waves/SIMD (lockstep generations, half work each).
// R7/R8 FAILED: acc[64]+64-wide W loses regalloc -> scratch storm.
// R9: dist-2 SWP of LDS frags: null (43.5%). Not in-wave LDS latency.
// R10: W via VMEM (k-major Wt): bank-conflicts halved (2.1M->1.05M) but
//     99.7us, VALU 41% -> DS-pipe theory FALSIFIED. All 4 structures pin at
//     ~41%: single wave/SIMD stalls ~60% on its serial dep chain.
// R11: real TLP at last: 2048 INDEPENDENT single-wave blocks (token-split
//     32t x 8hg), ZERO barriers (1 wave: program order + lgkmcnt), acc 4x8,
//     ~130 VGPR, 2.3KB LDS -> 3-4 waves/SIMD can reside, stalls decorrelate
//     (m114). Predict occupancy >=20%, VALUBusy 65-85%, logits 45-60us.

#define HDIM 4096
#define NEXP 64
#define NTOK 8192
#define HG 8
#define HSLAB (HDIM / HG)   // 512 k per block
#define KK 16               // k per staged chunk
#define NCH (HSLAB / KK)    // 32 chunks
#define TPBK 32             // tokens per block (half-wave tile)
#define XS 36               // LDS row stride (floats): 144B rows, 16B-aligned

// ---------------- kernel 0: W[64][4096] -> Wt[4096][64] ----------------
__global__ __launch_bounds__(64) void wtrans_kernel(
        const float* __restrict__ W, float* __restrict__ Wt) {
    __shared__ float t[64][65];
    const int kb = blockIdx.x * 64;
    const int lane = threadIdx.x;          // = expert e
    #pragma unroll
    for (int q = 0; q < 16; ++q) {
        float4 v = *reinterpret_cast<const float4*>(W + (size_t)lane * HDIM + kb + q * 4);
        t[lane][q * 4 + 0] = v.x; t[lane][q * 4 + 1] = v.y;
        t[lane][q * 4 + 2] = v.z; t[lane][q * 4 + 3] = v.w;
    }
    __syncthreads();
    #pragma unroll 4
    for (int k = 0; k < 64; ++k)
        Wt[(size_t)(kb + k) * NEXP + lane] = t[lane][k];
}

// ---------------- kernel 1: partial logits ----------------
__global__ __launch_bounds__(64) void logits_kernel(
        const float* __restrict__ X, const float* __restrict__ Wt,
        float* __restrict__ part) {
    const int tg   = blockIdx.x >> 3;   // 0..255
    const int hg   = blockIdx.x & 7;    // 0..7
    const int lane = threadIdx.x;       // 0..63
    const int tr   = lane >> 3;         // token-quad group 0..7
    const int ec   = lane & 7;          // expert-col group 0..7

    __shared__ __align__(16) float xs[KK * XS];   // 2304 B (x tile only)

    const int token0 = tg * TPBK;
    const int hbase  = hg * HSLAB;

    const int r2 = lane >> 1;           // token row 0..31 (staging)
    const int s  = lane & 1;            // col half 0..1 (8 floats each)

    float acc[4][8];
    #pragma unroll
    for (int i = 0; i < 4; ++i)
        #pragma unroll
        for (int j = 0; j < 8; ++j) acc[i][j] = 0.f;

    const float* Xb = X + (size_t)token0 * HDIM + hbase;
    const float* Wb = Wt + (size_t)hbase * NEXP + ec * 8;   // k-major rows

    float4 pfx[2];
    // ---- prologue: load + scatter x chunk 0 (32 rows x 16 k) ----
    #pragma unroll
    for (int q = 0; q < 2; ++q)
        pfx[q] = *reinterpret_cast<const float4*>(
            Xb + (size_t)r2 * HDIM + s * 8 + q * 4);
    #pragma unroll
    for (int q = 0; q < 2; ++q) {       // k-major scatter (2-way banks: s pairs)
        int kl = s * 8 + q * 4;
        xs[(kl + 0) * XS + r2] = pfx[q].x;
        xs[(kl + 1) * XS + r2] = pfx[q].y;
        xs[(kl + 2) * XS + r2] = pfx[q].z;
        xs[(kl + 3) * XS + r2] = pfx[q].w;
    }

    // ---- prime w pipeline: flat k = 0..3 (distance-4, 4 slots, VMEM/L2) ----
    float4 fw0[4], fw1[4];
    #pragma unroll
    for (int k = 0; k < 4; ++k) {
        const float4* wr = reinterpret_cast<const float4*>(Wb + (size_t)k * NEXP);
        fw0[k] = wr[0]; fw1[k] = wr[1];
    }
    // ---- prime x pipeline: chunk-local k = 0,1 (distance-2, LDS) ----
    float4 fx[2];
    #pragma unroll
    for (int k = 0; k < 2; ++k)
        fx[k] = *reinterpret_cast<const float4*>(xs + k * XS + tr * 4);

    for (int c = 0; c < NCH; ++c) {
        if (c + 1 < NCH) {              // global prefetch of next x chunk
            const int off = (c + 1) * KK;
            #pragma unroll
            for (int q = 0; q < 2; ++q)
                pfx[q] = *reinterpret_cast<const float4*>(
                    Xb + (size_t)r2 * HDIM + off + s * 8 + q * 4);
        }
        // ---- compute: per k, 1 LDS b128 (x) + 2 VMEM b128 (w, dist-4) ----
        #pragma unroll
        for (int k = 0; k < KK; ++k) {
            float xv[4] = {fx[k % 2].x, fx[k % 2].y, fx[k % 2].z, fx[k % 2].w};
            float wv[8] = {fw0[k % 4].x, fw0[k % 4].y, fw0[k % 4].z, fw0[k % 4].w,
                           fw1[k % 4].x, fw1[k % 4].y, fw1[k % 4].z, fw1[k % 4].w};
            #pragma unroll
            for (int i = 0; i < 4; ++i)
                #pragma unroll
                for (int j = 0; j < 8; ++j)
                    acc[i][j] = fmaf(xv[i], wv[j], acc[i][j]);
            // refill w slot k%4 with flat k+4 (clamped, L2-resident)
            {
                int kn = c * KK + k + 4;
                if (kn >= HSLAB) kn = HSLAB - 1;
                const float4* wr = reinterpret_cast<const float4*>(Wb + (size_t)kn * NEXP);
                fw0[k % 4] = wr[0]; fw1[k % 4] = wr[1];
            }
            // refill x slot k%2 with chunk-local k+2
            if (k + 2 < KK)
                fx[k % 2] = *reinterpret_cast<const float4*>(xs + (k + 2) * XS + tr * 4);
        }
        // ---- commit prefetched x chunk (single wave: lgkmcnt orders, no bar) ----
        if (c + 1 < NCH) {
            #pragma unroll
            for (int q = 0; q < 2; ++q) {
                int kl = s * 8 + q * 4;
                xs[(kl + 0) * XS + r2] = pfx[q].x;
                xs[(kl + 1) * XS + r2] = pfx[q].y;
                xs[(kl + 2) * XS + r2] = pfx[q].z;
                xs[(kl + 3) * XS + r2] = pfx[q].w;
            }
            // re-prime x slots for next chunk
            #pragma unroll
            for (int k = 0; k < 2; ++k)
                fx[k] = *reinterpret_cast<const float4*>(xs + k * XS + tr * 4);
        }
    }

    // ---- epilogue: per lane 4 tokens x 8 consecutive experts ----
    float* dst = part + ((size_t)hg * NTOK + token0) * NEXP;
    #pragma unroll
    for (int i = 0; i < 4; ++i) {
        int t = tr * 4 + i;
        *reinterpret_cast<float4*>(dst + (size_t)t * NEXP + ec * 8) =
            make_float4(acc[i][0], acc[i][1], acc[i][2], acc[i][3]);
        *reinterpret_cast<float4*>(dst + (size_t)t * NEXP + ec * 8 + 4) =
            make_float4(acc[i][4], acc[i][5], acc[i][6], acc[i][7]);
    }
}

// ---------------- kernel 2: reduce HG partials, top-2 softmax, scatter ----------------
__global__ __launch_bounds__(256) void topk_kernel(
        const float* __restrict__ part, float* __restrict__ probs,
        float* __restrict__ rmap) {
    const int wave = threadIdx.x >> 6;
    const int lane = threadIdx.x & 63;       // lane = expert
    const int token = blockIdx.x * 4 + wave;

    const float* p = part + (size_t)token * NEXP + lane;
    float v = 0.f;
    #pragma unroll
    for (int hg = 0; hg < HG; ++hg) v += p[(size_t)hg * NTOK * NEXP];

    // top-1 (lower index wins ties, like lax.top_k)
    float m1 = v; int i1 = lane;
    #pragma unroll
    for (int s = 32; s > 0; s >>= 1) {
        float om = __shfl_xor(m1, s, 64);
        int   oi = __shfl_xor(i1, s, 64);
        if (om > m1 || (om == m1 && oi < i1)) { m1 = om; i1 = oi; }
    }
    // top-2: exclude i1
    float vx = (lane == i1) ? -INFINITY : v;
    float m2 = vx; int i2 = lane;
    #pragma unroll
    for (int s = 32; s > 0; s >>= 1) {
        float om = __shfl_xor(m2, s, 64);
        int   oi = __shfl_xor(i2, s, 64);
        if (om > m2 || (om == m2 && oi < i2)) { m2 = om; i2 = oi; }
    }

    float e2 = expf(m2 - m1);
    float p1 = 1.f / (1.f + e2);
    float p2 = 1.f - p1;

    float prob = (lane == i1) ? p1 : ((lane == i2) ? p2 : 0.f);
    float flag = (lane == i1 || lane == i2) ? 1.f : 0.f;
    probs[(size_t)token * NEXP + lane] = prob;
    rmap [(size_t)token * NEXP + lane] = flag;
}

extern "C" void kernel_launch(void* const* d_in, const int* in_sizes, int n_in,
                              void* d_out, int out_size, void* d_ws, size_t ws_size,
                              hipStream_t stream) {
    const float* X = (const float*)d_in[0];   // [8192,4096]
    const float* W = (const float*)d_in[1];   // [64,4096]
    float* out  = (float*)d_out;
    float* part = (float*)d_ws;               // [8][8192][64] floats = 16MB
    float* Wt   = out;                        // 1MB scratch in d_out; logits
                                              // reads it before topk overwrites.

    wtrans_kernel<<<HDIM / 64, 64, 0, stream>>>(W, Wt);
    logits_kernel<<<256 * HG, 64, 0, stream>>>(X, Wt, part);
    topk_kernel<<<NTOK / 4, 256, 0, stream>>>(part, out, out + (size_t)NTOK * NEXP);
}

// Round 10
// 215.064 us; speedup vs baseline: 1.1707x; 1.1707x over previous
//
#include <hip/hip_runtime.h>
#include <math.h>

// MoE router: X[8192,4096] fp32 @ W^T -> logits[8192,64] -> top2 softmax scatter.
// d_out = probs[8192*64] ++ routing_map[8192*64] (floats).
// ws: part [8][8192][64] fp32 (16MB). Wb (bf16-split W frags, 1.5MB) in d_out scratch.
//
// R1-R11 (VALU fp32 family, all pinned 92-116us):
//   R5 best: 8x8 reg-tile via LDS, 92us, VALUBusy 41%, occupancy 10%.
//   R6 2-wave blocks: null. R9 SWP frag loads: null -> not in-wave latency.
//   R10 W via VMEM: bank-conflicts halved, still 41% -> DS pipe falsified.
//   R11 2048 indep waves, 2/SIMD: occupancy 19% but duty FELL to 27% ->
//     stalls correlated on shared per-CU resource. VALU-busy TIME conserved
//     (~31-38us = total instr issue) across all 6 structures. fp32-FMA floor
//     is 27.3us; family capped ~41% duty -> dead end.
// R12: change pipe: MFMA bf16 3-limb emulation (x=x1+x2+x3, w likewise, 6
//   product terms >= 2^-24; err ~1e-7 rel, 100x below tolerated fp32-reorder
//   diffs). 6x2.15 GMAC at 2075 TF = 12.4us MFMA floor; X-stream 128MB = 20us
//   HBM floor. Per wave 64tok x 64exp x 512k: acc 16x f32x4 (m89 C/D layout),
//   A-frags split in-register from dist-1 global X loads (NO LDS/barriers),
//   B pre-arranged in frag order by wprep (d_out scratch, R10-proven).
//   Predict logits 22-35us, MfmaUtil 8-15%, total ~160us.
//   (Resubmit: previous round was an infra failure, no data. Hazard audit
//   clean: no barriers anywhere in logits, OOB-checked, term schedule and
//   fragment layouts verified self-consistent.)

#define HDIM 4096
#define NEXP 64
#define NTOK 8192
#define HG 8
#define HSLAB (HDIM / HG)     // 512 k per block
#define NSTEP (HSLAB / 32)    // 16 K32 steps per block

typedef __attribute__((ext_vector_type(8)))  short    bf16x8;
typedef __attribute__((ext_vector_type(4)))  float    f32x4;
typedef __attribute__((ext_vector_type(4)))  unsigned u32x4;

union AFrag { unsigned u[4]; bf16x8 f; };
union BFrag { u32x4 v;       bf16x8 f; };

// RNE fp32 -> bf16, returned as the masked fp32 bit pattern (top 16 bits).
static __device__ __forceinline__ unsigned rne_mask(float x) {
    unsigned u = __float_as_uint(x);
    return (u + 0x7fffu + ((u >> 16) & 1u)) & 0xffff0000u;
}

#define SSTRIDE ((size_t)128 * 4 * 64 * 4)   // uints per split level

// ---------------- kernel 0: W[64][4096] -> Wb[3][128][4][64][8] bf16 frags ----
__global__ __launch_bounds__(256) void wprep_kernel(
        const float* __restrict__ W, unsigned* __restrict__ Wb) {
    const int kb = blockIdx.x;          // 0..127 (K32 window)
    const int c  = threadIdx.x >> 6;    // col-tile 0..3
    const int l  = threadIdx.x & 63;    // lane
    const int e  = c * 16 + (l & 15);   // expert = B col
    const int k0 = kb * 32 + (l >> 4) * 8;
    const float* src = W + (size_t)e * HDIM + k0;
    float a[8];
    #pragma unroll
    for (int j = 0; j < 8; ++j) a[j] = src[j];
    unsigned m1[8], m2[8], m3[8];
    #pragma unroll
    for (int j = 0; j < 8; ++j) {
        m1[j] = rne_mask(a[j]);
        float r1 = a[j] - __uint_as_float(m1[j]);
        m2[j] = rne_mask(r1);
        float r2 = r1 - __uint_as_float(m2[j]);
        m3[j] = rne_mask(r2);
    }
    size_t base = (((size_t)kb * 4 + c) * 64 + l) * 4;
    #pragma unroll
    for (int q = 0; q < 4; ++q) {
        Wb[0 * SSTRIDE + base + q] = m1[2*q+1] | (m1[2*q] >> 16);
        Wb[1 * SSTRIDE + base + q] = m2[2*q+1] | (m2[2*q] >> 16);
        Wb[2 * SSTRIDE + base + q] = m3[2*q+1] | (m3[2*q] >> 16);
    }
}

// ---------------- kernel 1: partial logits via bf16 MFMA x6 ----------------
#define LOAD_A(BUF, KB)                                                        \
    _Pragma("unroll")                                                          \
    for (int r = 0; r < 4; ++r) {                                              \
        const float* p = Xb + (size_t)(r * 16 + row) * HDIM + (KB) * 32 + kg * 8; \
        *(f32x4*)&BUF[r][0] = *(const f32x4*)p;                                \
        *(f32x4*)&BUF[r][4] = *(const f32x4*)(p + 4);                          \
    }

#define LOAD_B(BB, S, KBG)                                                     \
    _Pragma("unroll")                                                          \
    for (int c = 0; c < 4; ++c)                                                \
        BB[c].v = *(const u32x4*)(Wb + (S) * SSTRIDE +                         \
                                  (((size_t)(KBG) * 4 + c) * 64 + l) * 4);

// split with residual (levels 1,2): FR = bf16 limb, CUR -= limb (exact)
#define SPLIT_R(CUR, FR)                                                       \
    _Pragma("unroll")                                                          \
    for (int r = 0; r < 4; ++r) {                                              \
        unsigned m[8];                                                         \
        _Pragma("unroll")                                                      \
        for (int j = 0; j < 8; ++j) {                                          \
            m[j] = rne_mask(CUR[r][j]);                                        \
            CUR[r][j] -= __uint_as_float(m[j]);                                \
        }                                                                      \
        _Pragma("unroll")                                                      \
        for (int q = 0; q < 4; ++q) FR[r].u[q] = m[2*q+1] | (m[2*q] >> 16);    \
    }

// final split (level 3): no residual needed
#define SPLIT_N(CUR, FR)                                                       \
    _Pragma("unroll")                                                          \
    for (int r = 0; r < 4; ++r) {                                              \
        unsigned m[8];                                                         \
        _Pragma("unroll")                                                      \
        for (int j = 0; j < 8; ++j) m[j] = rne_mask(CUR[r][j]);                \
        _Pragma("unroll")                                                      \
        for (int q = 0; q < 4; ++q) FR[r].u[q] = m[2*q+1] | (m[2*q] >> 16);    \
    }

#define MFMA16(FR, BB)                                                         \
    _Pragma("unroll")                                                          \
    for (int r = 0; r < 4; ++r)                                                \
        _Pragma("unroll")                                                      \
        for (int c = 0; c < 4; ++c)                                            \
            acc[r][c] = __builtin_amdgcn_mfma_f32_16x16x32_bf16(               \
                FR[r].f, BB[c].f, acc[r][c], 0, 0, 0);

// terms: (x1,w1)(x1,w2)(x1,w3)(x2,w1)(x2,w2)(x3,w1); B dist-1 double-buffer
#define STEP(CUR, NXT, KB) {                                                   \
    if ((KB) + 1 < NSTEP) { LOAD_A(NXT, (KB) + 1); }                           \
    const int kbg = hg * NSTEP + (KB);                                         \
    LOAD_B(bb0, 0, kbg);                                                       \
    SPLIT_R(CUR, fr);            /* fr = x1, CUR = r1 */                       \
    LOAD_B(bb1, 1, kbg);                                                       \
    MFMA16(fr, bb0);             /* x1*w1 */                                   \
    LOAD_B(bb0, 2, kbg);                                                       \
    MFMA16(fr, bb1);             /* x1*w2 */                                   \
    LOAD_B(bb1, 0, kbg);                                                       \
    MFMA16(fr, bb0);             /* x1*w3 */                                   \
    SPLIT_R(CUR, fr);            /* fr = x2, CUR = r2 */                       \
    LOAD_B(bb0, 1, kbg);                                                       \
    MFMA16(fr, bb1);             /* x2*w1 */                                   \
    LOAD_B(bb1, 0, kbg);                                                       \
    MFMA16(fr, bb0);             /* x2*w2 */                                   \
    SPLIT_N(CUR, fr);            /* fr = x3 */                                 \
    MFMA16(fr, bb1);             /* x3*w1 */                                   \
}

__global__ __launch_bounds__(64) void logits_kernel(
        const float* __restrict__ X, const unsigned* __restrict__ Wb,
        float* __restrict__ part) {
    const int tg  = blockIdx.x >> 3;    // 0..127
    const int hg  = blockIdx.x & 7;     // 0..7
    const int l   = threadIdx.x;        // 0..63
    const int row = l & 15;             // A row / B col within 16-tile
    const int kg  = l >> 4;             // k subgroup 0..3

    const int token0 = tg * 64;
    const int kbase  = hg * HSLAB;

    f32x4 acc[4][4];
    #pragma unroll
    for (int r = 0; r < 4; ++r)
        #pragma unroll
        for (int c = 0; c < 4; ++c) acc[r][c] = (f32x4){0.f, 0.f, 0.f, 0.f};

    const float* Xb = X + (size_t)token0 * HDIM + kbase;

    float s0[4][8], s1[4][8];           // A fp32 staging, named ping-pong
    AFrag fr[4];
    BFrag bb0[4], bb1[4];

    LOAD_A(s0, 0);
    #pragma unroll 1
    for (int n = 0; n < NSTEP; n += 2) {
        STEP(s0, s1, n);
        STEP(s1, s0, n + 1);
    }

    // C/D layout (m89, HW-verified): col = lane&15, row = (lane>>4)*4 + i
    float* dst = part + ((size_t)hg * NTOK + token0) * NEXP;
    #pragma unroll
    for (int r = 0; r < 4; ++r)
        #pragma unroll
        for (int i = 0; i < 4; ++i) {
            int t = r * 16 + kg * 4 + i;
            #pragma unroll
            for (int c = 0; c < 4; ++c)
                dst[(size_t)t * NEXP + c * 16 + row] = acc[r][c][i];
        }
}

// ---------------- kernel 2: reduce HG partials, top-2 softmax, scatter ----------------
__global__ __launch_bounds__(256) void topk_kernel(
        const float* __restrict__ part, float* __restrict__ probs,
        float* __restrict__ rmap) {
    const int wave = threadIdx.x >> 6;
    const int lane = threadIdx.x & 63;       // lane = expert
    const int token = blockIdx.x * 4 + wave;

    const float* p = part + (size_t)token * NEXP + lane;
    float v = 0.f;
    #pragma unroll
    for (int hg = 0; hg < HG; ++hg) v += p[(size_t)hg * NTOK * NEXP];

    // top-1 (lower index wins ties, like lax.top_k)
    float m1 = v; int i1 = lane;
    #pragma unroll
    for (int s = 32; s > 0; s >>= 1) {
        float om = __shfl_xor(m1, s, 64);
        int   oi = __shfl_xor(i1, s, 64);
        if (om > m1 || (om == m1 && oi < i1)) { m1 = om; i1 = oi; }
    }
    // top-2: exclude i1
    float vx = (lane == i1) ? -INFINITY : v;
    float m2 = vx; int i2 = lane;
    #pragma unroll
    for (int s = 32; s > 0; s >>= 1) {
        float om = __shfl_xor(m2, s, 64);
        int   oi = __shfl_xor(i2, s, 64);
        if (om > m2 || (om == m2 && oi < i2)) { m2 = om; i2 = oi; }
    }

    float e2 = expf(m2 - m1);
    float p1 = 1.f / (1.f + e2);
    float p2 = 1.f - p1;

    float prob = (lane == i1) ? p1 : ((lane == i2) ? p2 : 0.f);
    float flag = (lane == i1 || lane == i2) ? 1.f : 0.f;
    probs[(size_t)token * NEXP + lane] = prob;
    rmap [(size_t)token * NEXP + lane] = flag;
}

extern "C" void kernel_launch(void* const* d_in, const int* in_sizes, int n_in,
                              void* d_out, int out_size, void* d_ws, size_t ws_size,
                              hipStream_t stream) {
    const float* X = (const float*)d_in[0];   // [8192,4096]
    const float* W = (const float*)d_in[1];   // [64,4096]
    float* out  = (float*)d_out;
    float* part = (float*)d_ws;               // [8][8192][64] floats = 16MB
    unsigned* Wb = (unsigned*)d_out;          // 1.5MB frag scratch in d_out;
                                              // consumed before topk overwrites.

    wprep_kernel<<<128, 256, 0, stream>>>(W, Wb);
    logits_kernel<<<128 * HG, 64, 0, stream>>>(X, Wb, part);
    topk_kernel<<<NTOK / 4, 256, 0, stream>>>(part, out, out + (size_t)NTOK * NEXP);
}